// Round 6
// baseline (159.923 us; speedup 1.0000x reference)
//
#include <hip/hip_runtime.h>
#include <cstdint>

#define DIM 128
#define NCEN 8

typedef __attribute__((ext_vector_type(8))) short short8;   // 8 bf16 = 4 VGPR
typedef __attribute__((ext_vector_type(4))) float f32x4;

constexpr int BLOCK = 256;
constexpr int WAVES = 4;
constexpr int RPG = 8;       // rows per wave-group
constexpr int GROUPS = 4;
constexpr int ROWS_PER_BLOCK = WAVES * RPG * GROUPS;   // 128
constexpr int ROW_BYTES = 512;   // output row slot: z bf16 in [0,256), vn @256

__device__ __forceinline__ unsigned bf16rne(float f) {
    unsigned u = __float_as_uint(f);
    return (u + 0x7FFFu + ((u >> 16) & 1u)) >> 16;
}
__device__ __forceinline__ float rdlane(float v, int srclane) {
    return __int_as_float(__builtin_amdgcn_readlane(__float_as_int(v), srclane));
}

// ---------------- Phase 1: norm -> rotate (exact f32 chain) -> quantize -> z ----------------
__global__ __launch_bounds__(BLOCK, 2)
void pq_phase1(const float* __restrict__ x,
               const float* __restrict__ Pi,
               const float* __restrict__ cen,
               char* __restrict__ zout)
{
    // p2: pair-interleaved Pi. Chunk (p,q) = 16B {Pi[2p][2q], Pi[2p+1][2q],
    // Pi[2p][2q+1], Pi[2p+1][2q+1]} at float-offset p*256 + ((q*4) ^ ((p&7)<<2)).
    // Lane p reads its own column pair; 8-lane phases cover all 32 banks.
    __shared__ __align__(16) float p2[DIM * DIM];           // 64 KB
    __shared__ __align__(16) float xbuf[WAVES][RPG][DIM];   // 16 KB (raw x, norm only)

    const int tid  = threadIdx.x;
    const int wave = tid >> 6;
    const int lane = tid & 63;
    const int row  = lane >> 3;   // x-row within group this lane co-owns
    const int jl   = lane & 7;    // 16-element chunk owner within the row

    float cv[NCEN];
#pragma unroll
    for (int i = 0; i < NCEN; ++i) cv[i] = cen[i];

    // ---- stage P2 (values bit-preserved, only permuted/interleaved) ----
#pragma unroll
    for (int i = 0; i < 16; ++i) {
        int chunk = i * BLOCK + tid;            // 0..4095
        int p = chunk >> 6, q = chunk & 63;
        float2 r0 = *reinterpret_cast<const float2*>(Pi + (size_t)(2 * p) * DIM + 2 * q);
        float2 r1 = *reinterpret_cast<const float2*>(Pi + (size_t)(2 * p + 1) * DIM + 2 * q);
        int off = p * 256 + ((q * 4) ^ ((p & 7) << 2));
        *reinterpret_cast<float4*>(p2 + off) = make_float4(r0.x, r1.x, r0.y, r1.y);
    }
    __syncthreads();

    const int row_block = blockIdx.x * ROWS_PER_BLOCK + wave * (RPG * GROUPS);
    const int d0 = 2 * lane;                    // this lane's output column pair

    // prologue: load group 0's raw x (16 elems per lane)
    float xr_[16], xn_[16];
    {
        const float* xp = x + (size_t)(row_block + row) * DIM + jl * 16;
#pragma unroll
        for (int c = 0; c < 4; ++c)
            *reinterpret_cast<float4*>(&xr_[4 * c]) =
                *reinterpret_cast<const float4*>(xp + 4 * c);
    }

    for (int g = 0; g < GROUPS; ++g) {
        const int r0row = row_block + g * RPG;

        // ---- raw x -> xbuf (for numpy-order norm) ----
#pragma unroll
        for (int c = 0; c < 4; ++c)
            *reinterpret_cast<float4*>(&xbuf[wave][row][jl * 16 + 4 * c]) =
                *reinterpret_cast<const float4*>(&xr_[4 * c]);

        // ---- f32 norm, numpy pairwise order: accumulator a=jl gets the 16
        //      sequential terms x[a+8t]^2, then ((r0+r1)+(r2+r3))+((r4+r5)+(r6+r7)) ----
        const float* xrow = &xbuf[wave][row][0];
        float v0  = xrow[jl];
        float racc = __fmul_rn(v0, v0);
#pragma unroll
        for (int t = 1; t < 16; ++t) {
            float v = xrow[jl + 8 * t];
            racc = __fadd_rn(racc, __fmul_rn(v, v));
        }
        racc = __fadd_rn(racc, __shfl_xor(racc, 1, 64));
        racc = __fadd_rn(racc, __shfl_xor(racc, 2, 64));
        racc = __fadd_rn(racc, __shfl_xor(racc, 4, 64));
        float vn  = __fsqrt_rn(racc);
        float vne = __fadd_rn(vn, 1e-8f);
        if (jl == 0)
            *reinterpret_cast<float*>(zout + (size_t)(r0row + row) * ROW_BYTES + 256) = vn;

        // ---- xn = x / (norm+eps), IEEE f32 division; stays in registers ----
#pragma unroll
        for (int c = 0; c < 16; ++c) xr_[c] = __fdiv_rn(xr_[c], vne);

        // ---- prefetch next group's raw x ----
        if (g + 1 < GROUPS) {
            const float* xp = x + (size_t)(r0row + RPG + row) * DIM + jl * 16;
#pragma unroll
            for (int c = 0; c < 4; ++c)
                *reinterpret_cast<float4*>(&xn_[4 * c]) =
                    *reinterpret_cast<const float4*>(xp + 4 * c);
        }

        // ---- matmul1: x broadcast via readlane->SGPR, Pi pairs from LDS.
        //      Each accumulator is a single ascending-k FMA chain (bit-exact). ----
        float2 acc[RPG];
#pragma unroll
        for (int r = 0; r < RPG; ++r) acc[r] = make_float2(0.f, 0.f);

        const float* prow = p2 + lane * 256;
        const int    swz  = (lane & 7) << 2;
        for (int kb = 0; kb < 8; ++kb) {        // 16 k per iteration (not unrolled)
            float4 pv[8];
#pragma unroll
            for (int qq = 0; qq < 8; ++qq)
                pv[qq] = *reinterpret_cast<const float4*>(prow + ((((kb * 8 + qq) * 4)) ^ swz));
#pragma unroll
            for (int kc = 0; kc < 16; ++kc) {   // k = kb*16 + kc
                const float plo = (kc & 1) ? pv[kc >> 1].z : pv[kc >> 1].x;
                const float phi = (kc & 1) ? pv[kc >> 1].w : pv[kc >> 1].y;
#pragma unroll
                for (int r = 0; r < RPG; ++r) {
                    float sx = rdlane(xr_[kc], r * 8 + kb);   // x[r][k], wave-uniform
                    acc[r].x = fmaf(sx, plo, acc[r].x);
                    acc[r].y = fmaf(sx, phi, acc[r].y);
                }
            }
        }

        // ---- quantize (f32 squared-distance argmin, first-min tie-break,
        //      f32 residual sign) + per-row reduce + z store, row by row ----
#pragma unroll
        for (int r = 0; r < RPG; ++r) {
            float q0, q1, s0, s1, as;
            {
                const float xrv = acc[r].x;
                float dd   = __fsub_rn(xrv, cv[0]);
                float best = __fmul_rn(dd, dd);
                q0 = cv[0];
#pragma unroll
                for (int i = 1; i < NCEN; ++i) {
                    float di = __fsub_rn(xrv, cv[i]);
                    float d2 = __fmul_rn(di, di);
                    bool  c  = d2 < best;
                    best = c ? d2 : best;
                    q0   = c ? cv[i] : q0;
                }
                float res = __fsub_rn(xrv, q0);
                s0 = (res >= 0.f) ? 1.f : -1.f;
                as = fabsf(res);
            }
            {
                const float xrv = acc[r].y;
                float dd   = __fsub_rn(xrv, cv[0]);
                float best = __fmul_rn(dd, dd);
                q1 = cv[0];
#pragma unroll
                for (int i = 1; i < NCEN; ++i) {
                    float di = __fsub_rn(xrv, cv[i]);
                    float d2 = __fmul_rn(di, di);
                    bool  c  = d2 < best;
                    best = c ? d2 : best;
                    q1   = c ? cv[i] : q1;
                }
                float res = __fsub_rn(xrv, q1);
                s1 = (res >= 0.f) ? 1.f : -1.f;
                as += fabsf(res);
            }
            // residual scale: order-free (smooth path) 64-lane butterfly
#pragma unroll
            for (int m = 1; m < 64; m <<= 1) as += __shfl_xor(as, m, 64);
            const float sc = as * (1.0f / 128.0f);            // /128 exact
            float z0 = __fadd_rn(q0, sc * s0);                // mul by +-1 exact
            float z1 = __fadd_rn(q1, sc * s1);
            unsigned pz = bf16rne(z0) | (bf16rne(z1) << 16);
            *reinterpret_cast<unsigned*>(
                zout + (size_t)(r0row + r) * ROW_BYTES + (size_t)d0 * 2) = pz;
        }

#pragma unroll
        for (int c = 0; c < 16; ++c) xr_[c] = xn_[c];
    }
}

// ---------------- Phase 2: out = (z @ Pi) * vn via bf16 MFMA (smooth path) ----------------
constexpr int BBLOCK = 256;
constexpr int BROWS  = 256;   // rows per block (4 waves x 4 iters x 16 rows)

__global__ __launch_bounds__(BBLOCK, 8)
void pq_phase2(const float* __restrict__ Pi, char* __restrict__ zio)
{
    // piT[n][k] = bf16(Pi[k][n]), element k stored at k ^ ((n&7)<<3)
    __shared__ __align__(16) unsigned short piT[DIM * DIM];   // 32 KB

    const int tid  = threadIdx.x;
    const int wave = tid >> 6;
    const int lane = tid & 63;

    // ---- stage transposed bf16 Pi (4x4 subtiles per thread) ----
#pragma unroll
    for (int s = 0; s < 4; ++s) {
        int sub = tid + s * BBLOCK;       // 0..1023
        int a4 = (sub & 31) * 4;          // k base
        int b4 = (sub >> 5) * 4;          // n base
        float rv[4][4];
#pragma unroll
        for (int i = 0; i < 4; ++i)
            *reinterpret_cast<float4*>(rv[i]) =
                *reinterpret_cast<const float4*>(Pi + (size_t)(a4 + i) * DIM + b4);
#pragma unroll
        for (int j = 0; j < 4; ++j) {
            const int n   = b4 + j;
            const int ksw = a4 ^ ((n & 7) << 3);
            unsigned lo = bf16rne(rv[0][j]) | (bf16rne(rv[1][j]) << 16);
            unsigned hi = bf16rne(rv[2][j]) | (bf16rne(rv[3][j]) << 16);
            *reinterpret_cast<uint2*>(&piT[n * DIM + ksw]) = make_uint2(lo, hi);
        }
    }
    __syncthreads();

    const int rowbase0 = blockIdx.x * BROWS;

    for (int it = 0; it < BROWS / 64; ++it) {
        const int rowbase = rowbase0 + it * 64 + wave * 16;

        const char* zr = zio + (size_t)(rowbase + (lane & 15)) * ROW_BYTES + ((lane >> 4) * 16);
        short8 afr[4];
#pragma unroll
        for (int kf = 0; kf < 4; ++kf)
            afr[kf] = *reinterpret_cast<const short8*>(zr + kf * 64);

        float vnr[4];
#pragma unroll
        for (int q = 0; q < 4; ++q)
            vnr[q] = *reinterpret_cast<const float*>(
                zio + (size_t)(rowbase + (lane >> 4) * 4 + q) * ROW_BYTES + 256);

#pragma unroll
        for (int nt = 0; nt < 8; ++nt) {
            const int n = nt * 16 + (lane & 15);
            f32x4 acc = {0.f, 0.f, 0.f, 0.f};
#pragma unroll
            for (int kf = 0; kf < 4; ++kf) {
                const int k0  = kf * 32 + (lane >> 4) * 8;
                const int ksw = k0 ^ ((n & 7) << 3);
                short8 bfr = *reinterpret_cast<const short8*>(&piT[n * DIM + ksw]);
                acc = __builtin_amdgcn_mfma_f32_16x16x32_bf16(afr[kf], bfr, acc, 0, 0, 0);
            }
#pragma unroll
            for (int q = 0; q < 4; ++q) {
                float o = __fmul_rn(acc[q], vnr[q]);
                *reinterpret_cast<float*>(
                    zio + (size_t)(rowbase + (lane >> 4) * 4 + q) * ROW_BYTES
                        + (size_t)(nt * 16 + (lane & 15)) * 4) = o;
            }
        }
    }
}

extern "C" void kernel_launch(void* const* d_in, const int* in_sizes, int n_in,
                              void* d_out, int out_size, void* d_ws, size_t ws_size,
                              hipStream_t stream) {
    const float* x   = (const float*)d_in[0];
    const float* Pi  = (const float*)d_in[1];
    const float* cen = (const float*)d_in[2];
    char* outp       = (char*)d_out;

    const int n_rows = in_sizes[0] / DIM;

    hipLaunchKernelGGL(pq_phase1, dim3(n_rows / ROWS_PER_BLOCK), dim3(BLOCK), 0, stream,
                       x, Pi, cen, outp);
    hipLaunchKernelGGL(pq_phase2, dim3(n_rows / BROWS), dim3(BBLOCK), 0, stream,
                       Pi, outp);
}